// Round 10
// baseline (394.266 us; speedup 1.0000x reference)
//
#include <hip/hip_runtime.h>
#include <hip/hip_bf16.h>

// ---- problem constants ----
#define BB 512
#define SS 49
#define DD 448
#define HH 8
#define QKVO 1536
#define MLPH 1792
#define MM (BB*SS)          // 25088 rows = 98 tiles of 256

using bf16_t = __hip_bfloat16;
typedef __attribute__((ext_vector_type(8))) short short8;   // bf16x8 MFMA frag
typedef __attribute__((ext_vector_type(4))) float f32x4;    // MFMA acc

__device__ __forceinline__ void gload_lds16(const void* g, void* l) {
  __builtin_amdgcn_global_load_lds(
      (const __attribute__((address_space(1))) void*)g,
      (__attribute__((address_space(3))) void*)l,
      16, 0, 0);
}

// ---------------- LDS-tiled transpose+cast: dst[C][R] bf16 = src[R][C] f32 ----------------
__global__ __launch_bounds__(256) void transpose_cast(const float* __restrict__ src,
                                                      bf16_t* __restrict__ dst,
                                                      int R, int C)
{
  __shared__ float tile[32][33];
  const int tx = threadIdx.x & 31, ty = threadIdx.x >> 5;   // ty 0..7
  const int c0 = blockIdx.x * 32, r0 = blockIdx.y * 32;
#pragma unroll
  for (int i = 0; i < 4; ++i)
    tile[ty + i*8][tx] = src[(size_t)(r0 + ty + i*8) * C + c0 + tx];
  __syncthreads();
#pragma unroll
  for (int i = 0; i < 4; ++i)
    dst[(size_t)(c0 + ty + i*8) * R + r0 + tx] = __float2bfloat16(tile[tx][ty + i*8]);
}

// ---------------- bias table expand to padded [8][64][64] bf16 ----------------
__global__ __launch_bounds__(256) void biasprep_kernel(const float* __restrict__ ab,
                                                       const int* __restrict__ idxs,
                                                       bf16_t* __restrict__ bias_pad)
{
  int idx = blockIdx.x * 256 + threadIdx.x;   // 32768
  int h = idx >> 12, r = (idx >> 6) & 63, c = idx & 63;
  float v = (r < SS && c < SS) ? ab[h*49 + idxs[r*49 + c]] : -1e30f;
  bias_pad[idx] = __float2bfloat16(v);
}

// ---------------- layernorm: one wave per row of 448 ----------------
__global__ __launch_bounds__(256) void ln_kernel(const float* __restrict__ x,
                                                 const float* __restrict__ g,
                                                 const float* __restrict__ b,
                                                 bf16_t* __restrict__ out)
{
  const int w = threadIdx.x >> 6, lane = threadIdx.x & 63;
  const int row = blockIdx.x * 4 + w;
  const float* xr = x + (size_t)row * DD;
  float v[7];
  float s = 0.f;
#pragma unroll
  for (int j = 0; j < 7; ++j) { v[j] = xr[lane + 64*j]; s += v[j]; }
#pragma unroll
  for (int off = 32; off; off >>= 1) s += __shfl_xor(s, off, 64);
  const float mu = s * (1.0f/448.0f);
  float q = 0.f;
#pragma unroll
  for (int j = 0; j < 7; ++j) { float d = v[j] - mu; q += d*d; }
#pragma unroll
  for (int off = 32; off; off >>= 1) q += __shfl_xor(q, off, 64);
  const float rstd = rsqrtf(q * (1.0f/448.0f) + 1e-5f);
  bf16_t* orow = out + (size_t)row * DD;
#pragma unroll
  for (int j = 0; j < 7; ++j) {
    int c = lane + 64*j;
    orow[c] = __float2bfloat16((v[j] - mu) * rstd * g[c] + b[c]);
  }
}

enum { EP_BF16 = 0, EP_RES1 = 1, EP_GELU = 2, EP_RES2 = 3 };

// ---------------- 256x256 8-wave 8-phase counted-vmcnt GEMM ----------------
// C = A(MxK) @ Bt(NxK)^T. BK=64; LDS = 2 buffers x 64KB, each buffer =
// quarters {A0,A1,B0,B1} of 16KB = [128 rows][64 k] bf16, chunk-XOR-swizzled
// (phys16Bchunk = logical ^ (row&7); staged linear via pre-swizzled global src).
// Per K-tile T: 4 phases, each {ds_read A-quadrant (+B in ph0) | stage-issue |
// barrier | lgkmcnt(0) | setprio(1) 16 MFMA}; T+1's quarters issued at the
// prior boundary (B-halves) and phase 1 (A-halves). Boundary: issue T+2's
// B-halves into buf[T&1] (readers done at ph3 barrier), then vmcnt(4):
// outstanding = T+1's 8 + 4 just issued -> oldest 8 (all of T+1) landed,
// 4 stay in flight. vmcnt never 0 except the tail. Each wave waits its OWN
// vmcnt then s_barrier -> all waves' stages landed before any read.
template<int EPI>
__global__ __launch_bounds__(512, 2) void gemm8_bf16(
    const bf16_t* __restrict__ A, const bf16_t* __restrict__ Bt,
    const float* __restrict__ bias, const float* __restrict__ resid,
    const float* __restrict__ ls, bf16_t* __restrict__ Obf,
    float* __restrict__ Of, int N, int K, int gy)
{
  extern __shared__ __align__(16) char lds[];   // 131072
  const int t = threadIdx.x;
  const int lane = t & 63;
  const int w = t >> 6;            // 0..7
  const int wm = w >> 2;           // 0..1  (rows wm*128)
  const int wn = w & 3;            // 0..3  (cols wn*64)
  const int fr = lane & 15, fq = lane >> 4;

  // bijective XCD swizzle (m204), n-fast decomposition
  const int nwg = gridDim.x;
  const int q8 = nwg >> 3, r8 = nwg & 7;
  const int xcd = blockIdx.x & 7, bix = blockIdx.x >> 3;
  const int wg = (xcd < r8 ? xcd*(q8+1) : r8*(q8+1) + (xcd-r8)*q8) + bix;
  const int m0 = (wg / gy) * 256;
  const int n0 = (wg % gy) * 256;

  const int NT = K >> 6;

  // ---- staging geometry: thread t covers rows {t>>3, 64+(t>>3)} x chunk t&7
  const int sr0 = t >> 3;
  const int cge = ((t & 7) ^ (sr0 & 7)) * 8;     // pre-swizzled k-offset (elements)
  const bf16_t* gq[4][2];                         // [quarter][j]: 0=B0,1=B1,2=A0,3=A1
#pragma unroll
  for (int h = 0; h < 2; ++h) {
    int rb0 = n0 + h*128 + sr0;      if (rb0 >= N) rb0 = N - 1;
    int rb1 = n0 + h*128 + 64 + sr0; if (rb1 >= N) rb1 = N - 1;
    gq[h][0]   = Bt + (size_t)rb0 * K + cge;
    gq[h][1]   = Bt + (size_t)rb1 * K + cge;
    gq[2+h][0] = A  + (size_t)(m0 + h*128 + sr0) * K + cge;
    gq[2+h][1] = A  + (size_t)(m0 + h*128 + 64 + sr0) * K + cge;
  }
  const int qoff[4] = {32768, 49152, 0, 16384};   // B0,B1,A0,A1 within a buffer

#define STAGE_Q(bb, qq, ko) do { \
    gload_lds16(gq[qq][0] + (ko), lds + (bb)*65536 + qoff[qq] + w*1024); \
    gload_lds16(gq[qq][1] + (ko), lds + (bb)*65536 + qoff[qq] + 8192 + w*1024); \
  } while (0)

  // ---- frag-read constant offsets
  const int cx0 = ((fq)     ^ (fr & 7)) * 16;     // ks=0 chunk byte off
  const int cx1 = ((4 + fq) ^ (fr & 7)) * 16;     // ks=1
  int bo[4];                                      // B-frag base offsets (per ni)
#pragma unroll
  for (int ni = 0; ni < 4; ++ni) {
    const int rbb = wn*64 + ni*16 + fr;           // 0..255
    bo[ni] = 32768 + (rbb >> 7)*16384 + (rbb & 127)*128;
  }

  f32x4 acc[8][4];
#pragma unroll
  for (int i = 0; i < 8; ++i)
#pragma unroll
    for (int j = 0; j < 4; ++j)
      acc[i][j] = f32x4{0.f, 0.f, 0.f, 0.f};

  // ---- prologue: T0 all quarters + T1 B-halves; vmcnt(4) -> T0 landed
  STAGE_Q(0, 0, 0); STAGE_Q(0, 1, 0); STAGE_Q(0, 2, 0); STAGE_Q(0, 3, 0);
  STAGE_Q(1, 0, 64); STAGE_Q(1, 1, 64);
  asm volatile("s_waitcnt vmcnt(4)" ::: "memory");
  __builtin_amdgcn_sched_barrier(0);
  __builtin_amdgcn_s_barrier();
  __builtin_amdgcn_sched_barrier(0);

  for (int T = 0; T < NT; ++T) {
    const int b = T & 1;
    const char* base = lds + b * 65536;
    short8 bfr[4][2];
#pragma unroll
    for (int q2 = 0; q2 < 4; ++q2) {
      // ds_reads: A-quadrant (m-frags 2q2, 2q2+1); B all (phase 0 only)
      short8 af[2][2];
#pragma unroll
      for (int j = 0; j < 2; ++j) {
        const int ro = wm*16384 + ((q2*2 + j)*16 + fr)*128;
        af[j][0] = *(const short8*)(base + ro + cx0);
        af[j][1] = *(const short8*)(base + ro + cx1);
      }
      if (q2 == 0) {
#pragma unroll
        for (int ni = 0; ni < 4; ++ni) {
          bfr[ni][0] = *(const short8*)(base + bo[ni] + cx0);
          bfr[ni][1] = *(const short8*)(base + bo[ni] + cx1);
        }
      }
      // stage: T+1's A-halves during phase 1 (B-halves went at the boundary)
      if (q2 == 1 && T + 1 < NT) {
        const int ko = (T + 1) * 64;
        STAGE_Q(b ^ 1, 2, ko);
        STAGE_Q(b ^ 1, 3, ko);
      }
      __builtin_amdgcn_sched_barrier(0);
      __builtin_amdgcn_s_barrier();
      asm volatile("s_waitcnt lgkmcnt(0)" ::: "memory");
      __builtin_amdgcn_sched_barrier(0);
      __builtin_amdgcn_s_setprio(1);
#pragma unroll
      for (int ks = 0; ks < 2; ++ks)
#pragma unroll
        for (int j = 0; j < 2; ++j)
#pragma unroll
          for (int ni = 0; ni < 4; ++ni)
            acc[q2*2 + j][ni] = __builtin_amdgcn_mfma_f32_16x16x32_bf16(
                af[j][ks], bfr[ni][ks], acc[q2*2 + j][ni], 0, 0, 0);
      __builtin_amdgcn_s_setprio(0);
      __builtin_amdgcn_sched_barrier(0);
      __builtin_amdgcn_s_barrier();
      __builtin_amdgcn_sched_barrier(0);
    }
    // ---- tile boundary: stage T+2's B-halves into buf b (readers of b done
    // at the phase-3 barrier above), counted wait for T+1.
    if (T + 1 < NT) {
      if (T + 2 < NT) {
        const int ko2 = (T + 2) * 64;
        STAGE_Q(b, 0, ko2);
        STAGE_Q(b, 1, ko2);
        asm volatile("s_waitcnt vmcnt(4)" ::: "memory");
      } else {
        asm volatile("s_waitcnt vmcnt(0)" ::: "memory");   // tail drain
      }
      __builtin_amdgcn_sched_barrier(0);
      __builtin_amdgcn_s_barrier();
      __builtin_amdgcn_sched_barrier(0);
    }
  }
#undef STAGE_Q

  // ---- epilogue: D col = lane&15, row = fq*4 + ri ----
#pragma unroll
  for (int mi = 0; mi < 8; ++mi) {
#pragma unroll
    for (int ni = 0; ni < 4; ++ni) {
      const int col = n0 + wn*64 + ni*16 + fr;
      if (col < N) {
        const float bc = bias[col];
        const int row0 = m0 + wm*128 + mi*16 + fq*4;
#pragma unroll
        for (int ri = 0; ri < 4; ++ri) {
          const size_t o = (size_t)(row0 + ri) * N + col;
          const float v = acc[mi][ni][ri] + bc;
          if constexpr (EPI == EP_BF16) {
            Obf[o] = __float2bfloat16(v);
          } else if constexpr (EPI == EP_GELU) {
            Obf[o] = __float2bfloat16(0.5f * v * (1.0f + erff(v * 0.7071067811865475f)));
          } else if constexpr (EPI == EP_RES1) {
            Of[o] = resid[o] + ls[col] * v;
          } else { // EP_RES2
            Of[o] = Of[o] + ls[col] * v;
          }
        }
      }
    }
  }
}

// ---------------- attention via MFMA: one wave per (b,h) ----------------
__global__ __launch_bounds__(64) void attn_mfma_kernel(const bf16_t* __restrict__ qkv,
                                                       const bf16_t* __restrict__ bias_pad,
                                                       bf16_t* __restrict__ ctx)
{
  __shared__ __align__(16) bf16_t VsF[64*128];
  __shared__ __align__(16) bf16_t PsF[64*72];
  const int b = blockIdx.x >> 3, h = blockIdx.x & 7;
  const int l = threadIdx.x;
  const int fr = l & 15, g = l >> 4;
  const size_t base = ((size_t)b * SS) * QKVO + (size_t)h * 192;

  // stage V (rows >= 49 duplicate row 48: finite, and P there is exactly 0)
  for (int c = l; c < 1024; c += 64) {
    const int j = c >> 4, ch = c & 15;
    const int jc = j < SS ? j : SS - 1;
    short8 v = *(const short8*)(qkv + base + (size_t)jc * QKVO + 64 + ch*8);
    *(short8*)(&VsF[j*128 + ((ch ^ (j >> 3)) & 15)*8]) = v;
  }

  // QK^T: fragments straight from global (row-major [s][32] == frag layout)
  short8 qf[4], kf[4];
#pragma unroll
  for (int mi = 0; mi < 4; ++mi) {
    int qr = mi*16 + fr; if (qr > SS-1) qr = SS-1;
    qf[mi] = *(const short8*)(qkv + base + (size_t)qr * QKVO + g*8);
    int kr = mi*16 + fr; if (kr > SS-1) kr = SS-1;
    kf[mi] = *(const short8*)(qkv + base + (size_t)kr * QKVO + 32 + g*8);
  }
  f32x4 sc[4][4];
#pragma unroll
  for (int mi = 0; mi < 4; ++mi)
#pragma unroll
    for (int ni = 0; ni < 4; ++ni)
      sc[mi][ni] = f32x4{0.f,0.f,0.f,0.f};
#pragma unroll
  for (int mi = 0; mi < 4; ++mi)
#pragma unroll
    for (int ni = 0; ni < 4; ++ni)
      sc[mi][ni] = __builtin_amdgcn_mfma_f32_16x16x32_bf16(qf[mi], kf[ni], sc[mi][ni], 0, 0, 0);

  // scale + bias + row softmax (rows live in 16-lane groups)
  const float scale = 0.17677669529663687f;   // 32^-0.5
  const bf16_t* bp = bias_pad + (size_t)h * 4096;
#pragma unroll
  for (int mi = 0; mi < 4; ++mi) {
#pragma unroll
    for (int ri = 0; ri < 4; ++ri) {
      const int r = mi*16 + g*4 + ri;
      float v0 = sc[mi][0][ri]*scale + __bfloat162float(bp[r*64 +      fr]);
      float v1 = sc[mi][1][ri]*scale + __bfloat162float(bp[r*64 + 16 + fr]);
      float v2 = sc[mi][2][ri]*scale + __bfloat162float(bp[r*64 + 32 + fr]);
      float v3 = sc[mi][3][ri]*scale + __bfloat162float(bp[r*64 + 48 + fr]);
      float m = fmaxf(fmaxf(v0, v1), fmaxf(v2, v3));
#pragma unroll
      for (int off = 8; off; off >>= 1) m = fmaxf(m, __shfl_xor(m, off, 64));
      v0 = __expf(v0 - m); v1 = __expf(v1 - m);
      v2 = __expf(v2 - m); v3 = __expf(v3 - m);
      float s = v0 + v1 + v2 + v3;
#pragma unroll
      for (int off = 8; off; off >>= 1) s += __shfl_xor(s, off, 64);
      const float inv = 1.0f / s;
      PsF[r*72 +      fr] = __float2bfloat16(v0 * inv);
      PsF[r*72 + 16 + fr] = __float2bfloat16(v1 * inv);
      PsF[r*72 + 32 + fr] = __float2bfloat16(v2 * inv);
      PsF[r*72 + 48 + fr] = __float2bfloat16(v3 * inv);
    }
  }
  __syncthreads();

  // PV: A = P (LDS b128 frags), B = V (swizzled scalar gather)
  short8 pf[4][2];
#pragma unroll
  for (int mi = 0; mi < 4; ++mi)
#pragma unroll
    for (int ks = 0; ks < 2; ++ks)
      pf[mi][ks] = *(const short8*)(&PsF[(mi*16 + fr)*72 + ks*32 + g*8]);

#pragma unroll
  for (int ni = 0; ni < 8; ++ni) {
    const int e = ni*16 + fr;
    short8 vf[2];
#pragma unroll
    for (int ks = 0; ks < 2; ++ks) {
      const int jb = ks*32 + g*8;
#pragma unroll
      for (int jj = 0; jj < 8; ++jj) {
        const int j = jb + jj;
        const int ch = ((e >> 3) ^ (j >> 3)) & 15;
        vf[ks][jj] = *(const short*)(&VsF[j*128 + ch*8 + (e & 7)]);
      }
    }
    f32x4 acc2[4];
#pragma unroll
    for (int mi = 0; mi < 4; ++mi) acc2[mi] = f32x4{0.f,0.f,0.f,0.f};
#pragma unroll
    for (int ks = 0; ks < 2; ++ks)
#pragma unroll
      for (int mi = 0; mi < 4; ++mi)
        acc2[mi] = __builtin_amdgcn_mfma_f32_16x16x32_bf16(pf[mi][ks], vf[ks], acc2[mi], 0, 0, 0);
#pragma unroll
    for (int mi = 0; mi < 4; ++mi) {
#pragma unroll
      for (int ri = 0; ri < 4; ++ri) {
        const int q = mi*16 + g*4 + ri;
        if (q < SS)
          ctx[((size_t)b * SS + q) * 1024 + h*128 + e] = __float2bfloat16(acc2[mi][ri]);
      }
    }
  }
}

// ---------------- launch ----------------
extern "C" void kernel_launch(void* const* d_in, const int* in_sizes, int n_in,
                              void* d_out, int out_size, void* d_ws, size_t ws_size,
                              hipStream_t stream) {
  const float* x      = (const float*)d_in[0];
  const float* ln1_g  = (const float*)d_in[1];
  const float* ln1_b  = (const float*)d_in[2];
  const float* qkv_w  = (const float*)d_in[3];
  const float* qkv_b  = (const float*)d_in[4];
  const float* ab     = (const float*)d_in[5];
  const float* proj_w = (const float*)d_in[6];
  const float* proj_b = (const float*)d_in[7];
  const float* ln2_g  = (const float*)d_in[8];
  const float* ln2_b  = (const float*)d_in[9];
  const float* w1     = (const float*)d_in[10];
  const float* b1     = (const float*)d_in[11];
  const float* w2     = (const float*)d_in[12];
  const float* b2     = (const float*)d_in[13];
  const float* ls1    = (const float*)d_in[14];
  const float* ls2    = (const float*)d_in[15];
  const int*   idxs   = (const int*)d_in[16];
  float* out = (float*)d_out;
  char* ws = (char*)d_ws;

  // workspace layout (bytes, 256-aligned)
  bf16_t* h_buf    = (bf16_t*)(ws);                       // 22,478,848
  bf16_t* qkv_buf  = (bf16_t*)(ws + 22478848);            // 77,070,336
  bf16_t* ctx_buf  = (bf16_t*)(ws + 99549184);            // 51,380,224
  bf16_t* m_buf    = (bf16_t*)(ws + 22478848);            // 89,915,392 (overlay qkv+ctx)
  bf16_t* qkv_wT   = (bf16_t*)(ws + 150929408);           // 1536x448
  bf16_t* proj_wT  = (bf16_t*)(ws + 152305664);           // 448x1024
  bf16_t* w1T      = (bf16_t*)(ws + 153223168);           // 1792x448
  bf16_t* w2T      = (bf16_t*)(ws + 154828800);           // 448x1792
  bf16_t* bias_pad = (bf16_t*)(ws + 156434432);           // 65,536 -> end 156,499,968

  hipFuncSetAttribute((const void*)&gemm8_bf16<EP_BF16>, hipFuncAttributeMaxDynamicSharedMemorySize, 131072);
  hipFuncSetAttribute((const void*)&gemm8_bf16<EP_RES1>, hipFuncAttributeMaxDynamicSharedMemorySize, 131072);
  hipFuncSetAttribute((const void*)&gemm8_bf16<EP_GELU>, hipFuncAttributeMaxDynamicSharedMemorySize, 131072);
  hipFuncSetAttribute((const void*)&gemm8_bf16<EP_RES2>, hipFuncAttributeMaxDynamicSharedMemorySize, 131072);

  transpose_cast<<<dim3(QKVO/32, DD/32),  256, 0, stream>>>(qkv_w,  qkv_wT,  DD,   QKVO);
  transpose_cast<<<dim3(DD/32, 1024/32),  256, 0, stream>>>(proj_w, proj_wT, 1024, DD);
  transpose_cast<<<dim3(MLPH/32, DD/32),  256, 0, stream>>>(w1,     w1T,     DD,   MLPH);
  transpose_cast<<<dim3(DD/32, MLPH/32),  256, 0, stream>>>(w2,     w2T,     MLPH, DD);
  biasprep_kernel<<<128, 256, 0, stream>>>(ab, idxs, bias_pad);

  ln_kernel<<<MM/4, 256, 0, stream>>>(x, ln1_g, ln1_b, h_buf);

  // qkv: M=25088 (98x256), N=1536 (6 n-tiles), K=448 (NT=7)
  gemm8_bf16<EP_BF16><<<98*6, 512, 131072, stream>>>(
      h_buf, qkv_wT, qkv_b, nullptr, nullptr, qkv_buf, nullptr, QKVO, DD, 6);

  attn_mfma_kernel<<<BB*HH, 64, 0, stream>>>(qkv_buf, bias_pad, ctx_buf);

  // proj: N=448 (2 n-tiles w/ pad), K=1024 (NT=16)
  gemm8_bf16<EP_RES1><<<98*2, 512, 131072, stream>>>(
      ctx_buf, proj_wT, proj_b, x, ls1, nullptr, out, DD, 1024, 2);

  ln_kernel<<<MM/4, 256, 0, stream>>>(out, ln2_g, ln2_b, h_buf);

  // mlp1: N=1792 (7 n-tiles), K=448 (NT=7)
  gemm8_bf16<EP_GELU><<<98*7, 512, 131072, stream>>>(
      h_buf, w1T, b1, nullptr, nullptr, m_buf, nullptr, MLPH, DD, 7);

  // mlp2: N=448 (2 n-tiles w/ pad), K=1792 (NT=28)
  gemm8_bf16<EP_RES2><<<98*2, 512, 131072, stream>>>(
      m_buf, w2T, b2, nullptr, ls2, nullptr, out, DD, MLPH, 2);
}

// Round 11
// 324.822 us; speedup vs baseline: 1.2138x; 1.2138x over previous
//
#include <hip/hip_runtime.h>
#include <hip/hip_bf16.h>

// ---- problem constants ----
#define BB 512
#define SS 49
#define DD 448
#define HH 8
#define QKVO 1536
#define MLPH 1792
#define MM (BB*SS)          // 25088 rows

using bf16_t = __hip_bfloat16;
typedef __attribute__((ext_vector_type(8))) short short8;   // bf16x8 MFMA frag
typedef __attribute__((ext_vector_type(4))) float f32x4;    // MFMA acc

__device__ __forceinline__ void gload_lds16(const void* g, void* l) {
  __builtin_amdgcn_global_load_lds(
      (const __attribute__((address_space(1))) void*)g,
      (__attribute__((address_space(3))) void*)l,
      16, 0, 0);
}

// ---------------- merged prep: weight transposes+cast + bias expand ----------------
__global__ void prep_kernel(const float* __restrict__ qkv_w, const float* __restrict__ proj_w,
                            const float* __restrict__ w1, const float* __restrict__ w2,
                            const float* __restrict__ ab, const int* __restrict__ idxs,
                            bf16_t* __restrict__ qkv_wT, bf16_t* __restrict__ proj_wT,
                            bf16_t* __restrict__ w1T, bf16_t* __restrict__ w2T,
                            bf16_t* __restrict__ bias_pad)
{
  int idx = blockIdx.x * 256 + threadIdx.x;
  if (idx < 688128) {                       // qkv_wT[n*448+k] = qkv_w[k*1536+n]
    int n = idx / 448, k = idx % 448;
    qkv_wT[idx] = __float2bfloat16(qkv_w[k*1536 + n]);
  } else if ((idx -= 688128) < 458752) {    // proj_wT[n*1024+k] = proj_w[k*448+n]
    int n = idx / 1024, k = idx % 1024;
    proj_wT[idx] = __float2bfloat16(proj_w[k*448 + n]);
  } else if ((idx -= 458752) < 802816) {    // w1T[n*448+k] = w1[k*1792+n]
    int n = idx / 448, k = idx % 448;
    w1T[idx] = __float2bfloat16(w1[k*1792 + n]);
  } else if ((idx -= 802816) < 802816) {    // w2T[n*1792+k] = w2[k*448+n]
    int n = idx / 1792, k = idx % 1792;
    w2T[idx] = __float2bfloat16(w2[k*448 + n]);
  } else if ((idx -= 802816) < 32768) {     // bias_pad[h][r][c], pad = -1e30
    int h = idx >> 12, r = (idx >> 6) & 63, c = idx & 63;
    float v = (r < SS && c < SS) ? ab[h*49 + idxs[r*49 + c]] : -1e30f;
    bias_pad[idx] = __float2bfloat16(v);
  }
}

// ---------------- layernorm (LN1): one wave per row of 448 ----------------
__global__ __launch_bounds__(256) void ln_kernel(const float* __restrict__ x,
                                                 const float* __restrict__ g,
                                                 const float* __restrict__ b,
                                                 bf16_t* __restrict__ out)
{
  const int w = threadIdx.x >> 6, lane = threadIdx.x & 63;
  const int row = blockIdx.x * 4 + w;
  const float* xr = x + (size_t)row * DD;
  float v[7];
  float s = 0.f;
#pragma unroll
  for (int j = 0; j < 7; ++j) { v[j] = xr[lane + 64*j]; s += v[j]; }
#pragma unroll
  for (int off = 32; off; off >>= 1) s += __shfl_xor(s, off, 64);
  const float mu = s * (1.0f/448.0f);
  float q = 0.f;
#pragma unroll
  for (int j = 0; j < 7; ++j) { float d = v[j] - mu; q += d*d; }
#pragma unroll
  for (int off = 32; off; off >>= 1) q += __shfl_xor(q, off, 64);
  const float rstd = rsqrtf(q * (1.0f/448.0f) + 1e-5f);
  bf16_t* orow = out + (size_t)row * DD;
#pragma unroll
  for (int j = 0; j < 7; ++j) {
    int c = lane + 64*j;
    orow[c] = __float2bfloat16((v[j] - mu) * rstd * g[c] + b[c]);
  }
}

// ---------------- fused reduce1 + LN2: out = x + ls1*(p0+p1+bias); h2 = LN(out) ----------------
__global__ __launch_bounds__(256) void red1_ln2_kernel(
    const float* __restrict__ x, const bf16_t* __restrict__ p0,
    const bf16_t* __restrict__ p1, const float* __restrict__ pb,
    const float* __restrict__ ls1, const float* __restrict__ g,
    const float* __restrict__ b, float* __restrict__ out, bf16_t* __restrict__ h2)
{
  const int w = threadIdx.x >> 6, lane = threadIdx.x & 63;
  const int row = blockIdx.x * 4 + w;
  const float* xr = x + (size_t)row * DD;
  const bf16_t* p0r = p0 + (size_t)row * DD;
  const bf16_t* p1r = p1 + (size_t)row * DD;
  float* orow = out + (size_t)row * DD;
  float v[7];
  float s = 0.f;
#pragma unroll
  for (int j = 0; j < 7; ++j) {
    const int c = lane + 64*j;
    const float pv = __bfloat162float(p0r[c]) + __bfloat162float(p1r[c]) + pb[c];
    v[j] = xr[c] + ls1[c] * pv;
    orow[c] = v[j];
    s += v[j];
  }
#pragma unroll
  for (int off = 32; off; off >>= 1) s += __shfl_xor(s, off, 64);
  const float mu = s * (1.0f/448.0f);
  float q = 0.f;
#pragma unroll
  for (int j = 0; j < 7; ++j) { float d = v[j] - mu; q += d*d; }
#pragma unroll
  for (int off = 32; off; off >>= 1) q += __shfl_xor(q, off, 64);
  const float rstd = rsqrtf(q * (1.0f/448.0f) + 1e-5f);
  bf16_t* hrow = h2 + (size_t)row * DD;
#pragma unroll
  for (int j = 0; j < 7; ++j) {
    const int c = lane + 64*j;
    hrow[c] = __float2bfloat16((v[j] - mu) * rstd * g[c] + b[c]);
  }
}

// ---------------- reduce2: out += ls2*(q0+q1+bias) ----------------
__global__ __launch_bounds__(256) void red2_kernel(
    const bf16_t* __restrict__ q0, const bf16_t* __restrict__ q1,
    const float* __restrict__ pb, const float* __restrict__ ls2,
    float* __restrict__ out)
{
  const int w = threadIdx.x >> 6, lane = threadIdx.x & 63;
  const int row = blockIdx.x * 4 + w;
  const bf16_t* q0r = q0 + (size_t)row * DD;
  const bf16_t* q1r = q1 + (size_t)row * DD;
  float* orow = out + (size_t)row * DD;
#pragma unroll
  for (int j = 0; j < 7; ++j) {
    const int c = lane + 64*j;
    const float pv = __bfloat162float(q0r[c]) + __bfloat162float(q1r[c]) + pb[c];
    orow[c] = orow[c] + ls2[c] * pv;
  }
}

enum { EP_BF16 = 0, EP_GELU = 2, EP_PART = 4 };

// ---------------- 128x128 4-wave GEMM (R6-proven) with optional block split-K ----------------
// BK=64, single 32KB LDS, stage->sync->compute->sync. XCD chunk swizzle
// (grid %8==0), n-fast/split-innermost decomposition -> A panels L2-local.
// NSPLIT=2: block s covers K-half s; EP_PART writes bf16 partial to P0/P1.
template<int EPI, int NSPLIT>
__global__ __launch_bounds__(256, 2) void gemmr_bf16(
    const bf16_t* __restrict__ A, const bf16_t* __restrict__ Bt,
    const float* __restrict__ bias, bf16_t* __restrict__ O0,
    bf16_t* __restrict__ O1, int N, int K, int gy)
{
  __shared__ __align__(16) char lds[32768];
  const int t = threadIdx.x;
  const int lane = t & 63;
  const int w = t >> 6;

  const int chunk = gridDim.x >> 3;
  const int swz = (blockIdx.x & 7) * chunk + (blockIdx.x >> 3);
  const int m0 = (swz / (gy * NSPLIT)) * 128;
  const int rr = swz % (gy * NSPLIT);
  const int n0 = (rr / NSPLIT) * 128;
  const int sp = rr % NSPLIT;
  const int ksub = K / NSPLIT;
  const int kbase = sp * ksub;

  const int fr = lane & 15;          // frag row (A) / col (B)
  const int fq = lane >> 4;          // k-quad
  const int wm = (w >> 1) * 64;
  const int wn = (w & 1) * 64;

  f32x4 acc[4][4];
#pragma unroll
  for (int i = 0; i < 4; ++i)
#pragma unroll
    for (int j = 0; j < 4; ++j)
      acc[i][j] = f32x4{0.f, 0.f, 0.f, 0.f};

  const int rsub = t >> 3;                   // 0..31
  const int g8 = (t & 7) ^ (rsub & 7);       // pre-swizzled global k-chunk
  const int wbase = w * 1024;                // wave-uniform LDS base
  const int nkt = ksub >> 6;

  const bf16_t* gA[4];
  const bf16_t* gB[4];
#pragma unroll
  for (int i = 0; i < 4; ++i) {
    gA[i] = A + (size_t)(m0 + i*32 + rsub) * K + kbase + g8*8;
    int rb = n0 + i*32 + rsub;
    if (rb >= N) rb = N - 1;                 // clamp pad rows
    gB[i] = Bt + (size_t)rb * K + kbase + g8*8;
  }

  for (int kt = 0; kt < nkt; ++kt) {
    const int ko = kt << 6;
#pragma unroll
    for (int i = 0; i < 4; ++i) {
      gload_lds16(gA[i] + ko, lds + i*4096 + wbase);
      gload_lds16(gB[i] + ko, lds + 16384 + i*4096 + wbase);
    }
    __syncthreads();
#pragma unroll
    for (int kk = 0; kk < 2; ++kk) {
      short8 af[4], bfr[4];
#pragma unroll
      for (int i = 0; i < 4; ++i) {
        const int ra = wm + i*16 + fr;
        const int ca = (fq + kk*4) ^ (ra & 7);
        af[i] = *(const short8*)(lds + ra*128 + ca*16);
        const int rb2 = wn + i*16 + fr;
        const int cb = (fq + kk*4) ^ (rb2 & 7);
        bfr[i] = *(const short8*)(lds + 16384 + rb2*128 + cb*16);
      }
#pragma unroll
      for (int mi = 0; mi < 4; ++mi)
#pragma unroll
        for (int ni = 0; ni < 4; ++ni)
          acc[mi][ni] = __builtin_amdgcn_mfma_f32_16x16x32_bf16(af[mi], bfr[ni], acc[mi][ni], 0, 0, 0);
    }
    __syncthreads();
  }

  // epilogue: D col = lane&15, row = fq*4 + ri
  bf16_t* P = (NSPLIT == 2 && sp == 1) ? O1 : O0;
#pragma unroll
  for (int mi = 0; mi < 4; ++mi) {
#pragma unroll
    for (int ni = 0; ni < 4; ++ni) {
      const int col = n0 + wn + ni*16 + fr;
      if (col < N) {
        float bc = 0.f;
        if constexpr (EPI != EP_PART) bc = bias[col];
        const int row0 = m0 + wm + mi*16 + fq*4;
#pragma unroll
        for (int ri = 0; ri < 4; ++ri) {
          const size_t o = (size_t)(row0 + ri) * N + col;
          const float v = acc[mi][ni][ri] + bc;
          if constexpr (EPI == EP_GELU) {
            P[o] = __float2bfloat16(0.5f * v * (1.0f + erff(v * 0.7071067811865475f)));
          } else { // EP_BF16 / EP_PART
            P[o] = __float2bfloat16(v);
          }
        }
      }
    }
  }
}

// ---------------- attention via MFMA: one wave per (b,h) ----------------
__global__ __launch_bounds__(64) void attn_mfma_kernel(const bf16_t* __restrict__ qkv,
                                                       const bf16_t* __restrict__ bias_pad,
                                                       bf16_t* __restrict__ ctx)
{
  __shared__ __align__(16) bf16_t VsF[64*128];
  __shared__ __align__(16) bf16_t PsF[64*72];
  const int b = blockIdx.x >> 3, h = blockIdx.x & 7;
  const int l = threadIdx.x;
  const int fr = l & 15, g = l >> 4;
  const size_t base = ((size_t)b * SS) * QKVO + (size_t)h * 192;

  // stage V (rows >= 49 duplicate row 48: finite, and P there is exactly 0)
  for (int c = l; c < 1024; c += 64) {
    const int j = c >> 4, ch = c & 15;
    const int jc = j < SS ? j : SS - 1;
    short8 v = *(const short8*)(qkv + base + (size_t)jc * QKVO + 64 + ch*8);
    *(short8*)(&VsF[j*128 + ((ch ^ (j >> 3)) & 15)*8]) = v;
  }

  // QK^T: fragments straight from global (row-major [s][32] == frag layout)
  short8 qf[4], kf[4];
#pragma unroll
  for (int mi = 0; mi < 4; ++mi) {
    int qr = mi*16 + fr; if (qr > SS-1) qr = SS-1;
    qf[mi] = *(const short8*)(qkv + base + (size_t)qr * QKVO + g*8);
    int kr = mi*16 + fr; if (kr > SS-1) kr = SS-1;
    kf[mi] = *(const short8*)(qkv + base + (size_t)kr * QKVO + 32 + g*8);
  }
  f32x4 sc[4][4];
#pragma unroll
  for (int mi = 0; mi < 4; ++mi)
#pragma unroll
    for (int ni = 0; ni < 4; ++ni)
      sc[mi][ni] = f32x4{0.f,0.f,0.f,0.f};
#pragma unroll
  for (int mi = 0; mi < 4; ++mi)
#pragma unroll
    for (int ni = 0; ni < 4; ++ni)
      sc[mi][ni] = __builtin_amdgcn_mfma_f32_16x16x32_bf16(qf[mi], kf[ni], sc[mi][ni], 0, 0, 0);

  // scale + bias + row softmax (rows live in 16-lane groups)
  const float scale = 0.17677669529663687f;   // 32^-0.5
  const bf16_t* bp = bias_pad + (size_t)h * 4096;
#pragma unroll
  for (int mi = 0; mi < 4; ++mi) {
#pragma unroll
    for (int ri = 0; ri < 4; ++ri) {
      const int r = mi*16 + g*4 + ri;
      float v0 = sc[mi][0][ri]*scale + __bfloat162float(bp[r*64 +      fr]);
      float v1 = sc[mi][1][ri]*scale + __bfloat162float(bp[r*64 + 16 + fr]);
      float v2 = sc[mi][2][ri]*scale + __bfloat162float(bp[r*64 + 32 + fr]);
      float v3 = sc[mi][3][ri]*scale + __bfloat162float(bp[r*64 + 48 + fr]);
      float m = fmaxf(fmaxf(v0, v1), fmaxf(v2, v3));
#pragma unroll
      for (int off = 8; off; off >>= 1) m = fmaxf(m, __shfl_xor(m, off, 64));
      v0 = __expf(v0 - m); v1 = __expf(v1 - m);
      v2 = __expf(v2 - m); v3 = __expf(v3 - m);
      float s = v0 + v1 + v2 + v3;
#pragma unroll
      for (int off = 8; off; off >>= 1) s += __shfl_xor(s, off, 64);
      const float inv = 1.0f / s;
      PsF[r*72 +      fr] = __float2bfloat16(v0 * inv);
      PsF[r*72 + 16 + fr] = __float2bfloat16(v1 * inv);
      PsF[r*72 + 32 + fr] = __float2bfloat16(v2 * inv);
      PsF[r*72 + 48 + fr] = __float2bfloat16(v3 * inv);
    }
  }
  __syncthreads();

  // PV: A = P (LDS b128 frags), B = V (swizzled scalar gather)
  short8 pf[4][2];
#pragma unroll
  for (int mi = 0; mi < 4; ++mi)
#pragma unroll
    for (int ks = 0; ks < 2; ++ks)
      pf[mi][ks] = *(const short8*)(&PsF[(mi*16 + fr)*72 + ks*32 + g*8]);

#pragma unroll
  for (int ni = 0; ni < 8; ++ni) {
    const int e = ni*16 + fr;
    short8 vf[2];
#pragma unroll
    for (int ks = 0; ks < 2; ++ks) {
      const int jb = ks*32 + g*8;
#pragma unroll
      for (int jj = 0; jj < 8; ++jj) {
        const int j = jb + jj;
        const int ch = ((e >> 3) ^ (j >> 3)) & 15;
        vf[ks][jj] = *(const short*)(&VsF[j*128 + ch*8 + (e & 7)]);
      }
    }
    f32x4 acc2[4];
#pragma unroll
    for (int mi = 0; mi < 4; ++mi) acc2[mi] = f32x4{0.f,0.f,0.f,0.f};
#pragma unroll
    for (int ks = 0; ks < 2; ++ks)
#pragma unroll
      for (int mi = 0; mi < 4; ++mi)
        acc2[mi] = __builtin_amdgcn_mfma_f32_16x16x32_bf16(pf[mi][ks], vf[ks], acc2[mi], 0, 0, 0);
#pragma unroll
    for (int mi = 0; mi < 4; ++mi) {
#pragma unroll
      for (int ri = 0; ri < 4; ++ri) {
        const int q = mi*16 + g*4 + ri;
        if (q < SS)
          ctx[((size_t)b * SS + q) * 1024 + h*128 + e] = __float2bfloat16(acc2[mi][ri]);
      }
    }
  }
}

// ---------------- launch ----------------
extern "C" void kernel_launch(void* const* d_in, const int* in_sizes, int n_in,
                              void* d_out, int out_size, void* d_ws, size_t ws_size,
                              hipStream_t stream) {
  const float* x      = (const float*)d_in[0];
  const float* ln1_g  = (const float*)d_in[1];
  const float* ln1_b  = (const float*)d_in[2];
  const float* qkv_w  = (const float*)d_in[3];
  const float* qkv_b  = (const float*)d_in[4];
  const float* ab     = (const float*)d_in[5];
  const float* proj_w = (const float*)d_in[6];
  const float* proj_b = (const float*)d_in[7];
  const float* ln2_g  = (const float*)d_in[8];
  const float* ln2_b  = (const float*)d_in[9];
  const float* w1     = (const float*)d_in[10];
  const float* b1     = (const float*)d_in[11];
  const float* w2     = (const float*)d_in[12];
  const float* b2     = (const float*)d_in[13];
  const float* ls1    = (const float*)d_in[14];
  const float* ls2    = (const float*)d_in[15];
  const int*   idxs   = (const int*)d_in[16];
  float* out = (float*)d_out;
  char* ws = (char*)d_ws;

  // workspace layout (bytes, 256-aligned)
  bf16_t* h_buf    = (bf16_t*)(ws);                       // 22,478,848 (h, then h2)
  bf16_t* qkv_buf  = (bf16_t*)(ws + 22478848);            // 77,070,336
  bf16_t* ctx_buf  = (bf16_t*)(ws + 99549184);            // 51,380,224
  bf16_t* m_buf    = (bf16_t*)(ws + 22478848);            // 89,915,392 (overlay, ends 112,394,240)
  bf16_t* p0       = (bf16_t*)(ws + 22478848);            // proj partial s=0 (qkv region, dead)
  bf16_t* p1       = (bf16_t*)(ws + 44957696);            // proj partial s=1
  bf16_t* q0       = (bf16_t*)(ws);                       // mlp2 partial s=0 (h region, dead)
  bf16_t* q1       = (bf16_t*)(ws + 112394240);           // mlp2 partial s=1 (gap after m_buf)
  bf16_t* qkv_wT   = (bf16_t*)(ws + 150929408);           // 1536x448
  bf16_t* proj_wT  = (bf16_t*)(ws + 152305664);           // 448x1024
  bf16_t* w1T      = (bf16_t*)(ws + 153223168);           // 1792x448
  bf16_t* w2T      = (bf16_t*)(ws + 154828800);           // 448x1792
  bf16_t* bias_pad = (bf16_t*)(ws + 156434432);           // 65,536 -> end 156,499,968

  const int prep_total = 688128 + 458752 + 802816 + 802816 + 32768;
  prep_kernel<<<(prep_total + 255)/256, 256, 0, stream>>>(
      qkv_w, proj_w, w1, w2, ab, idxs, qkv_wT, proj_wT, w1T, w2T, bias_pad);

  ln_kernel<<<MM/4, 256, 0, stream>>>(x, ln1_g, ln1_b, h_buf);

  // qkv: M=25088 (196x128), N=1536 (12), K=448
  gemmr_bf16<EP_BF16, 1><<<196*12, 256, 0, stream>>>(
      h_buf, qkv_wT, qkv_b, qkv_buf, nullptr, QKVO, DD, 12);

  attn_mfma_kernel<<<BB*HH, 64, 0, stream>>>(qkv_buf, bias_pad, ctx_buf);

  // proj split-K x2: N=448 (4 n-tiles), K=1024 -> ksub=512 (8 steps), grid 1568
  gemmr_bf16<EP_PART, 2><<<196*4*2, 256, 0, stream>>>(
      ctx_buf, proj_wT, nullptr, p0, p1, DD, 1024, 4);

  // fused: out = x + ls1*(p0+p1+proj_b); h2 = LN2(out)
  red1_ln2_kernel<<<MM/4, 256, 0, stream>>>(
      x, p0, p1, proj_b, ls1, ln2_g, ln2_b, out, h_buf);

  // mlp1: N=1792 (14), K=448
  gemmr_bf16<EP_GELU, 1><<<196*14, 256, 0, stream>>>(
      h_buf, w1T, b1, m_buf, nullptr, MLPH, DD, 14);

  // mlp2 split-K x2: N=448 (4), K=1792 -> ksub=896 (14 steps), grid 1568
  gemmr_bf16<EP_PART, 2><<<196*4*2, 256, 0, stream>>>(
      m_buf, w2T, nullptr, q0, q1, DD, MLPH, 4);

  // out += ls2*(q0+q1+b2)
  red2_kernel<<<MM/4, 256, 0, stream>>>(q0, q1, b2, ls2, out);
}